// Round 1
// baseline (3411.069 us; speedup 1.0000x reference)
//
#include <hip/hip_runtime.h>
#include <hip/hip_bf16.h>

typedef __attribute__((ext_vector_type(8))) short bf16x8;
typedef __attribute__((ext_vector_type(4))) float f32x4;

#define NBATCH 4096
#define SEQT 181
#define NFEAT 12
#define HDIM 128
#define ROWS 16
#define LSTR 136              // padded bf16 row stride (128+8): breaks LDS bank conflicts
#define OUTSTRIDE (SEQT*NFEAT)

// d_ws layout:
//   [0 .. 262144)          bf16 weight frags  [layer][wave][gate][kstep][lane][e]
//   [262144 .. 266240)     bf16 Wout frags    [kstep][lane][e]  (cols 12..15 zero)
//   byte 532480            f32 combined bias  [layer][512]  (bih+bhh)
//   byte 536576            f32 bout[16]       (12 used)
#define WFRAG_ELEMS 262144
#define WOUT_ELEMS  4096
#define BIAS_F32OFF (532480/4)
#define BOUT_F32OFF (536576/4)

__device__ __forceinline__ float fsig(float x) {
  return __builtin_amdgcn_rcpf(1.0f + __builtin_amdgcn_exp2f(-1.442695041f * x));
}
__device__ __forceinline__ float ftanh(float x) {
  float e = __builtin_amdgcn_exp2f(-2.885390082f * x);   // = exp(-2x)
  return __builtin_fmaf(2.0f, __builtin_amdgcn_rcpf(1.0f + e), -1.0f);
}
__device__ __forceinline__ unsigned short f2bf(float x) {
  __hip_bfloat16 h = __float2bfloat16(x);
  return __builtin_bit_cast(unsigned short, h);
}

// ---------------- setup: repack weights into MFMA B-fragment order (bf16) ----------------
__global__ void setup_kernel(const float* __restrict__ Wih0, const float* __restrict__ Whh0,
                             const float* __restrict__ bih0, const float* __restrict__ bhh0,
                             const float* __restrict__ Wih1, const float* __restrict__ Whh1,
                             const float* __restrict__ bih1, const float* __restrict__ bhh1,
                             const float* __restrict__ Wo,   const float* __restrict__ bo,
                             unsigned short* __restrict__ ws)
{
  int idx = blockIdx.x * blockDim.x + threadIdx.x;
  if (idx < WFRAG_ELEMS) {
    // B-frag for mfma_f32_16x16x32_bf16: B[k][col], lane holds col=lane&15, k=(lane>>4)*8+e
    int e = idx & 7, lane = (idx >> 3) & 63, s = (idx >> 9) & 7, g = (idx >> 12) & 3,
        w = (idx >> 14) & 7, l = idx >> 17;
    int row = g * 128 + w * 16 + (lane & 15);       // gate row in G = [Wih | Whh]
    int k   = s * 32 + (lane >> 4) * 8 + e;         // 0..255 over [x(128) | h(128)]
    const float* Wih = l ? Wih1 : Wih0;
    const float* Whh = l ? Whh1 : Whh0;
    float v = (k < HDIM) ? Wih[row * HDIM + k] : Whh[row * HDIM + (k - HDIM)];
    ws[idx] = f2bf(v);
  } else if (idx < WFRAG_ELEMS + WOUT_ELEMS) {
    int i2 = idx - WFRAG_ELEMS;
    int e = i2 & 7, lane = (i2 >> 3) & 63, s = i2 >> 9;
    int c = lane & 15;
    int k = s * 32 + (lane >> 4) * 8 + e;           // 0..255 over [z0(128) | z1(128)]
    float v = (c < NFEAT) ? Wo[c * 256 + k] : 0.0f;
    ws[idx] = f2bf(v);
  } else if (idx < WFRAG_ELEMS + WOUT_ELEMS + 1024) {
    int i3 = idx - (WFRAG_ELEMS + WOUT_ELEMS);
    int l = i3 >> 9, r = i3 & 511;
    float v = l ? (bih1[r] + bhh1[r]) : (bih0[r] + bhh0[r]);
    reinterpret_cast<float*>(ws)[BIAS_F32OFF + i3] = v;
  } else if (idx < WFRAG_ELEMS + WOUT_ELEMS + 1024 + 16) {
    int i4 = idx - (WFRAG_ELEMS + WOUT_ELEMS + 1024);
    reinterpret_cast<float*>(ws)[BOUT_F32OFF + i4] = (i4 < NFEAT) ? bo[i4] : 0.0f;
  }
}

// ---------------- main: 256 blocks x 512 threads; each block = 16 batch rows, all 181 steps ----------------
__global__ __launch_bounds__(512, 2) void lstm_kernel(
    const float* __restrict__ ench, const float* __restrict__ encc,
    const unsigned short* __restrict__ wfrag, const unsigned short* __restrict__ woutf,
    const float* __restrict__ biasc, const float* __restrict__ boutc,
    float* __restrict__ out)
{
  // buffers: 0,1 = x ping / 2,3 = x pong (z targets alternate), 4 = y0, 5 = y1 (h0 carry), 6 = enc_h[1] (t=0 h1)
  __shared__ __align__(16) unsigned short sb[7][ROWS][LSTR];
  const int tid  = threadIdx.x;
  const int wave = tid >> 6, lane = tid & 63;
  const int col  = lane & 15, lg = lane >> 4;
  const int n0   = blockIdx.x * ROWS;

  // zero x-ping buffers (dec_in0 = 0)
  for (int i = tid; i < 2 * ROWS * LSTR; i += 512) (&sb[0][0][0])[i] = 0;
  // load initial hidden states (bf16)
  for (int i = tid; i < ROWS * HDIM; i += 512) {
    int r = i >> 7, d = i & (HDIM - 1);
    sb[5][r][d] = f2bf(ench[(n0 + r) * HDIM + d]);                  // h layer 0
    sb[6][r][d] = f2bf(ench[NBATCH * HDIM + (n0 + r) * HDIM + d]);  // h layer 1
  }
  // c state in fp32 registers: lane holds rows lg*4+j, dim wave*16+col
  float c0[4], c1[4], bgv[2][4];
  #pragma unroll
  for (int j = 0; j < 4; ++j) {
    int r = n0 + lg * 4 + j, d = wave * 16 + col;
    c0[j] = encc[r * HDIM + d];
    c1[j] = encc[NBATCH * HDIM + r * HDIM + d];
  }
  #pragma unroll
  for (int l = 0; l < 2; ++l)
    #pragma unroll
    for (int g = 0; g < 4; ++g)
      bgv[l][g] = biasc[l * 512 + g * 128 + wave * 16 + col];
  const float bov = boutc[col];
  __syncthreads();

  const bf16x8* wfv = reinterpret_cast<const bf16x8*>(wfrag);
  const bf16x8* wl0 = wfv + (size_t)wave * (4 * 8 * 64);
  const bf16x8* wl1 = wfv + (size_t)(8 + wave) * (4 * 8 * 64);
  const bf16x8* wov = reinterpret_cast<const bf16x8*>(woutf);

  auto cell = [&](int xb, int hb, int ob, const bf16x8* wfl, const float* bgl, float* c) {
    bf16x8 a[8];
    #pragma unroll
    for (int s = 0; s < 4; ++s)
      a[s] = *reinterpret_cast<const bf16x8*>(&sb[xb][col][s * 32 + lg * 8]);
    #pragma unroll
    for (int s = 0; s < 4; ++s)
      a[4 + s] = *reinterpret_cast<const bf16x8*>(&sb[hb][col][s * 32 + lg * 8]);
    __syncthreads();                       // reads done before anyone writes ob
    f32x4 acc[4];
    #pragma unroll
    for (int g = 0; g < 4; ++g) acc[g] = (f32x4){bgl[g], bgl[g], bgl[g], bgl[g]};
    #pragma unroll
    for (int g = 0; g < 4; ++g) {
      #pragma unroll
      for (int s = 0; s < 8; ++s)
        acc[g] = __builtin_amdgcn_mfma_f32_16x16x32_bf16(a[s], wfl[(g * 8 + s) * 64 + lane], acc[g], 0, 0, 0);
    }
    // gates: acc[0]=i acc[1]=f acc[2]=g acc[3]=o ; per lane: 4 batch rows x 1 h-dim
    #pragma unroll
    for (int j = 0; j < 4; ++j) {
      float cn = fsig(acc[1][j]) * c[j] + fsig(acc[0][j]) * ftanh(acc[2][j]);
      c[j] = cn;
      sb[ob][lg * 4 + j][wave * 16 + col] = f2bf(fsig(acc[3][j]) * ftanh(cn));
    }
    __syncthreads();                       // writes visible before next cell reads
  };

  for (int t = 0; t < SEQT; ++t) {
    const int xA = (t & 1) ? 2 : 0, xB = xA + 1;
    const int zA = (t & 1) ? 0 : 2, zB = zA + 1;
    cell(xA, 5, 4, wl0, bgv[0], c0);                  // L0 t0: h0 in y1 -> y0
    cell(xB, 4, 5, wl0, bgv[0], c0);                  // L0 t1: h0 in y0 -> y1
    cell(4, (t == 0) ? 6 : xB, zA, wl1, bgv[1], c1);  // L1 t0: h1 = prev z1 (or enc_h[1]) -> zA
    cell(5, zA, zB, wl1, bgv[1], c1);                 // L1 t1: -> zB
    if (wave == 0) {                                  // output projection, one MFMA tile
      bf16x8 a[8];
      #pragma unroll
      for (int s = 0; s < 4; ++s) {
        a[s]     = *reinterpret_cast<const bf16x8*>(&sb[zA][col][s * 32 + lg * 8]);
        a[4 + s] = *reinterpret_cast<const bf16x8*>(&sb[zB][col][s * 32 + lg * 8]);
      }
      f32x4 po = (f32x4){bov, bov, bov, bov};
      #pragma unroll
      for (int s = 0; s < 8; ++s)
        po = __builtin_amdgcn_mfma_f32_16x16x32_bf16(a[s], wov[s * 64 + lane], po, 0, 0, 0);
      if (col < NFEAT) {
        #pragma unroll
        for (int j = 0; j < 4; ++j)
          out[(n0 + lg * 4 + j) * OUTSTRIDE + t * NFEAT + col] = fsig(po[j]);
      }
    }
  }
}

extern "C" void kernel_launch(void* const* d_in, const int* in_sizes, int n_in,
                              void* d_out, int out_size, void* d_ws, size_t ws_size,
                              hipStream_t stream) {
  const float* ench = (const float*)d_in[0];
  const float* encc = (const float*)d_in[1];
  const float* Wih0 = (const float*)d_in[2];
  const float* Whh0 = (const float*)d_in[3];
  const float* bih0 = (const float*)d_in[4];
  const float* bhh0 = (const float*)d_in[5];
  const float* Wih1 = (const float*)d_in[6];
  const float* Whh1 = (const float*)d_in[7];
  const float* bih1 = (const float*)d_in[8];
  const float* bhh1 = (const float*)d_in[9];
  const float* Wo   = (const float*)d_in[10];
  const float* bo   = (const float*)d_in[11];
  unsigned short* ws = (unsigned short*)d_ws;

  int total = WFRAG_ELEMS + WOUT_ELEMS + 1024 + 16;
  int blocks = (total + 511) / 512;
  hipLaunchKernelGGL(setup_kernel, dim3(blocks), dim3(512), 0, stream,
                     Wih0, Whh0, bih0, bhh0, Wih1, Whh1, bih1, bhh1, Wo, bo, ws);

  const unsigned short* wfrag = ws;
  const unsigned short* woutf = ws + WFRAG_ELEMS;
  const float* biasc = reinterpret_cast<const float*>(ws) + BIAS_F32OFF;
  const float* boutc = reinterpret_cast<const float*>(ws) + BOUT_F32OFF;

  hipLaunchKernelGGL(lstm_kernel, dim3(NBATCH / ROWS), dim3(512), 0, stream,
                     ench, encc, wfrag, woutf, biasc, boutc, (float*)d_out);
}

// Round 2
// 2297.408 us; speedup vs baseline: 1.4847x; 1.4847x over previous
//
#include <hip/hip_runtime.h>
#include <hip/hip_bf16.h>
#include <hip/hip_fp16.h>

typedef __attribute__((ext_vector_type(8))) short bf16x8;
typedef __attribute__((ext_vector_type(4))) float f32x4;

#define NBATCH 4096
#define SEQT 181
#define NFEAT 12
#define HDIM 128
#define ROWS 16
#define LSTR 136              // padded bf16 row stride for activations
#define OUTSTRIDE (SEQT*NFEAT)

// d_ws layout (unchanged from R1):
#define WFRAG_ELEMS 262144
#define WOUT_ELEMS  4096
#define BIAS_F32OFF (532480/4)
#define BOUT_F32OFF (536576/4)

// LDS layout: [0,131072) weight frags [8w][2l][4g][2si][64lane]*16B ; [131072,161536) activations [7][16][136] bf16
#define ACT_BYTEOFF 131072

__device__ __forceinline__ float fsig(float x) {
  return __builtin_amdgcn_rcpf(1.0f + __builtin_amdgcn_exp2f(-1.442695041f * x));
}
__device__ __forceinline__ float ftanh(float x) {
  float e = __builtin_amdgcn_exp2f(-2.885390082f * x);   // = exp(-2x)
  return __builtin_fmaf(2.0f, __builtin_amdgcn_rcpf(1.0f + e), -1.0f);
}
__device__ __forceinline__ unsigned short f2bf(float x) {
  __hip_bfloat16 h = __float2bfloat16(x);
  return __builtin_bit_cast(unsigned short, h);
}

// ---------------- setup: repack weights into MFMA fragment order (bf16) ----------------
__global__ void setup_kernel(const float* __restrict__ Wih0, const float* __restrict__ Whh0,
                             const float* __restrict__ bih0, const float* __restrict__ bhh0,
                             const float* __restrict__ Wih1, const float* __restrict__ Whh1,
                             const float* __restrict__ bih1, const float* __restrict__ bhh1,
                             const float* __restrict__ Wo,   const float* __restrict__ bo,
                             unsigned short* __restrict__ ws)
{
  int idx = blockIdx.x * blockDim.x + threadIdx.x;
  if (idx < WFRAG_ELEMS) {
    // frag: lane&15 = gate-dim (16 of them), k=(lane>>4)*8+e over [x(128)|h(128)]
    int e = idx & 7, lane = (idx >> 3) & 63, s = (idx >> 9) & 7, g = (idx >> 12) & 3,
        w = (idx >> 14) & 7, l = idx >> 17;
    int row = g * 128 + w * 16 + (lane & 15);
    int k   = s * 32 + (lane >> 4) * 8 + e;
    const float* Wih = l ? Wih1 : Wih0;
    const float* Whh = l ? Whh1 : Whh0;
    float v = (k < HDIM) ? Wih[row * HDIM + k] : Whh[row * HDIM + (k - HDIM)];
    ws[idx] = f2bf(v);
  } else if (idx < WFRAG_ELEMS + WOUT_ELEMS) {
    int i2 = idx - WFRAG_ELEMS;
    int e = i2 & 7, lane = (i2 >> 3) & 63, s = i2 >> 9;
    int c = lane & 15;
    int k = s * 32 + (lane >> 4) * 8 + e;           // k over [z0(128) | z1(128)]
    float v = (c < NFEAT) ? Wo[c * 256 + k] : 0.0f;
    ws[idx] = f2bf(v);
  } else if (idx < WFRAG_ELEMS + WOUT_ELEMS + 1024) {
    int i3 = idx - (WFRAG_ELEMS + WOUT_ELEMS);
    int l = i3 >> 9, r = i3 & 511;
    float v = l ? (bih1[r] + bhh1[r]) : (bih0[r] + bhh0[r]);
    reinterpret_cast<float*>(ws)[BIAS_F32OFF + i3] = v;
  } else if (idx < WFRAG_ELEMS + WOUT_ELEMS + 1024 + 16) {
    int i4 = idx - (WFRAG_ELEMS + WOUT_ELEMS + 1024);
    reinterpret_cast<float*>(ws)[BOUT_F32OFF + i4] = (i4 < NFEAT) ? bo[i4] : 0.0f;
  }
}

// ---------------- main: 256 blocks x 512 threads; weights CU-resident (VGPR+LDS) ----------------
__global__ __launch_bounds__(512, 2) void lstm_kernel(
    const float* __restrict__ ench, const float* __restrict__ encc,
    const unsigned short* __restrict__ wfrag, const unsigned short* __restrict__ woutf,
    const float* __restrict__ biasc, const float* __restrict__ boutc,
    float* __restrict__ out)
{
  __shared__ __align__(16) unsigned char smem[161536];
  bf16x8* wlds = reinterpret_cast<bf16x8*>(smem);
  unsigned short* act = reinterpret_cast<unsigned short*>(smem + ACT_BYTEOFF);

  const int tid  = threadIdx.x;
  const int wave = tid >> 6, lane = tid & 63;
  const int col  = lane & 15, lg = lane >> 4;
  const int n0   = blockIdx.x * ROWS;
  const int dbase = wave * 16 + lg * 4;      // this lane's 4 h-dims (D-layout rows)

  // ---- persistent weight fragments: s=0..5 in VGPRs, s=6..7 in LDS ----
  bf16x8 wreg[2][4][6];
  const bf16x8* wfv = reinterpret_cast<const bf16x8*>(wfrag);
  #pragma unroll
  for (int l = 0; l < 2; ++l)
    #pragma unroll
    for (int g = 0; g < 4; ++g) {
      #pragma unroll
      for (int s = 0; s < 6; ++s)
        wreg[l][g][s] = wfv[(size_t)((((l * 8 + wave) * 4 + g) * 8) + s) * 64 + lane];
      #pragma unroll
      for (int si = 0; si < 2; ++si)
        wlds[(((wave * 2 + l) * 4 + g) * 2 + si) * 64 + lane] =
            wfv[(size_t)((((l * 8 + wave) * 4 + g) * 8) + 6 + si) * 64 + lane];
    }

  // zero x-ping buffers 0,1 (dec_in0 = 0)
  for (int i = tid; i < 2 * ROWS * LSTR; i += 512) act[i] = 0;
  // initial hidden states, [row][dim] bf16
  for (int i = tid; i < ROWS * HDIM; i += 512) {
    int r = i >> 7, d = i & (HDIM - 1);
    act[(5 * ROWS + r) * LSTR + d] = f2bf(ench[(n0 + r) * HDIM + d]);
    act[(6 * ROWS + r) * LSTR + d] = f2bf(ench[(NBATCH + n0 + r) * HDIM + d]);
  }
  // c-state: lane holds (batch = n0+col, dims dbase..dbase+3) as f32
  f32x4 c0 = *reinterpret_cast<const f32x4*>(&encc[(size_t)(n0 + col) * HDIM + dbase]);
  f32x4 c1 = *reinterpret_cast<const f32x4*>(&encc[(size_t)(NBATCH + n0 + col) * HDIM + dbase]);
  // bias packed f16x2 (per-lane 4 dims x 4 gates x 2 layers) = 16 VGPRs
  __half2 bh[2][4][2];
  #pragma unroll
  for (int l = 0; l < 2; ++l)
    #pragma unroll
    for (int g = 0; g < 4; ++g) {
      f32x4 bv = *reinterpret_cast<const f32x4*>(&biasc[l * 512 + g * 128 + dbase]);
      bh[l][g][0] = __floats2half2_rn(bv[0], bv[1]);
      bh[l][g][1] = __floats2half2_rn(bv[2], bv[3]);
    }
  f32x4 bov = *reinterpret_cast<const f32x4*>(&boutc[lg * 4]);  // out bias (padded to 16)
  __syncthreads();

  const int aoffl = col * LSTR + lg * 8;     // per-lane activation B-frag base (ushort units)

  auto cell = [&](int xb, int hb, int ob, const bf16x8 (&wr)[4][6], int lb,
                  const __half2 (&bg)[4][2], f32x4& c) {
    const unsigned short* xp = act + xb * (ROWS * LSTR) + aoffl;
    const unsigned short* hp = act + hb * (ROWS * LSTR) + aoffl;
    f32x4 acc[4];
    #pragma unroll
    for (int g = 0; g < 4; ++g) {
      acc[g][0] = __low2float(bg[g][0]); acc[g][1] = __high2float(bg[g][0]);
      acc[g][2] = __low2float(bg[g][1]); acc[g][3] = __high2float(bg[g][1]);
    }
    #pragma unroll
    for (int s = 0; s < 4; ++s) {                       // k = x-half
      bf16x8 a = *reinterpret_cast<const bf16x8*>(&xp[s * 32]);
      #pragma unroll
      for (int g = 0; g < 4; ++g)
        acc[g] = __builtin_amdgcn_mfma_f32_16x16x32_bf16(wr[g][s], a, acc[g], 0, 0, 0);
    }
    #pragma unroll
    for (int s = 4; s < 6; ++s) {                       // k = h-half, VGPR frags
      bf16x8 a = *reinterpret_cast<const bf16x8*>(&hp[(s - 4) * 32]);
      #pragma unroll
      for (int g = 0; g < 4; ++g)
        acc[g] = __builtin_amdgcn_mfma_f32_16x16x32_bf16(wr[g][s], a, acc[g], 0, 0, 0);
    }
    #pragma unroll
    for (int si = 0; si < 2; ++si) {                    // k = h-half tail, LDS frags
      bf16x8 a = *reinterpret_cast<const bf16x8*>(&hp[(2 + si) * 32]);
      #pragma unroll
      for (int g = 0; g < 4; ++g) {
        bf16x8 wf = wlds[(lb + g * 2 + si) * 64 + lane];
        acc[g] = __builtin_amdgcn_mfma_f32_16x16x32_bf16(wf, a, acc[g], 0, 0, 0);
      }
    }
    // gates: i,f,g,o ; lane: batch col, dims dbase+j
    unsigned int p0, p1;
    {
      float cn0 = fsig(acc[1][0]) * c[0] + fsig(acc[0][0]) * ftanh(acc[2][0]);
      float cn1 = fsig(acc[1][1]) * c[1] + fsig(acc[0][1]) * ftanh(acc[2][1]);
      float cn2 = fsig(acc[1][2]) * c[2] + fsig(acc[0][2]) * ftanh(acc[2][2]);
      float cn3 = fsig(acc[1][3]) * c[3] + fsig(acc[0][3]) * ftanh(acc[2][3]);
      c[0] = cn0; c[1] = cn1; c[2] = cn2; c[3] = cn3;
      unsigned int h0 = f2bf(fsig(acc[3][0]) * ftanh(cn0));
      unsigned int h1 = f2bf(fsig(acc[3][1]) * ftanh(cn1));
      unsigned int h2 = f2bf(fsig(acc[3][2]) * ftanh(cn2));
      unsigned int h3 = f2bf(fsig(acc[3][3]) * ftanh(cn3));
      p0 = h0 | (h1 << 16); p1 = h2 | (h3 << 16);
    }
    uint2* op = reinterpret_cast<uint2*>(act + ob * (ROWS * LSTR) + col * LSTR + dbase);
    *op = make_uint2(p0, p1);                 // one ds_write_b64: 4 consecutive dims
    __syncthreads();
  };

  const int lb0 = (wave * 2 + 0) * 8;
  const int lb1 = (wave * 2 + 1) * 8;
  const bf16x8* wov = reinterpret_cast<const bf16x8*>(woutf);

  for (int t = 0; t < SEQT; ++t) {
    const int xA = (t & 1) ? 2 : 0, xB = xA + 1;
    const int zA = (t & 1) ? 0 : 2, zB = zA + 1;
    cell(xA, 5, 4, wreg[0], lb0, bh[0], c0);                  // L0 t0
    cell(xB, 4, 5, wreg[0], lb0, bh[0], c0);                  // L0 t1
    cell(4, (t == 0) ? 6 : xB, zA, wreg[1], lb1, bh[1], c1);  // L1 t0
    cell(5, zA, zB, wreg[1], lb1, bh[1], c1);                 // L1 t1
    if (wave == 0) {                                          // output projection
      const unsigned short* z0 = act + zA * (ROWS * LSTR) + aoffl;
      const unsigned short* z1 = act + zB * (ROWS * LSTR) + aoffl;
      f32x4 po = bov;
      #pragma unroll
      for (int s = 0; s < 8; ++s) {
        const unsigned short* zp = (s < 4) ? z0 : z1;
        bf16x8 a = *reinterpret_cast<const bf16x8*>(&zp[(s & 3) * 32]);
        po = __builtin_amdgcn_mfma_f32_16x16x32_bf16(wov[s * 64 + lane], a, po, 0, 0, 0);
      }
      if (lg < 3) {
        f32x4 r;
        r[0] = fsig(po[0]); r[1] = fsig(po[1]); r[2] = fsig(po[2]); r[3] = fsig(po[3]);
        *reinterpret_cast<f32x4*>(&out[(size_t)(n0 + col) * OUTSTRIDE + t * NFEAT + lg * 4]) = r;
      }
    }
  }
}

extern "C" void kernel_launch(void* const* d_in, const int* in_sizes, int n_in,
                              void* d_out, int out_size, void* d_ws, size_t ws_size,
                              hipStream_t stream) {
  const float* ench = (const float*)d_in[0];
  const float* encc = (const float*)d_in[1];
  const float* Wih0 = (const float*)d_in[2];
  const float* Whh0 = (const float*)d_in[3];
  const float* bih0 = (const float*)d_in[4];
  const float* bhh0 = (const float*)d_in[5];
  const float* Wih1 = (const float*)d_in[6];
  const float* Whh1 = (const float*)d_in[7];
  const float* bih1 = (const float*)d_in[8];
  const float* bhh1 = (const float*)d_in[9];
  const float* Wo   = (const float*)d_in[10];
  const float* bo   = (const float*)d_in[11];
  unsigned short* ws = (unsigned short*)d_ws;

  int total = WFRAG_ELEMS + WOUT_ELEMS + 1024 + 16;
  int blocks = (total + 511) / 512;
  hipLaunchKernelGGL(setup_kernel, dim3(blocks), dim3(512), 0, stream,
                     Wih0, Whh0, bih0, bhh0, Wih1, Whh1, bih1, bhh1, Wo, bo, ws);

  const unsigned short* wfrag = ws;
  const unsigned short* woutf = ws + WFRAG_ELEMS;
  const float* biasc = reinterpret_cast<const float*>(ws) + BIAS_F32OFF;
  const float* boutc = reinterpret_cast<const float*>(ws) + BOUT_F32OFF;

  hipLaunchKernelGGL(lstm_kernel, dim3(NBATCH / ROWS), dim3(512), 0, stream,
                     ench, encc, wfrag, woutf, biasc, boutc, (float*)d_out);
}

// Round 3
// 2138.938 us; speedup vs baseline: 1.5947x; 1.0741x over previous
//
#include <hip/hip_runtime.h>
#include <hip/hip_bf16.h>

typedef __attribute__((ext_vector_type(8))) short bf16x8;
typedef __attribute__((ext_vector_type(4))) float f32x4;

#define NBATCH 4096
#define SEQT 181
#define NFEAT 12
#define HDIM 128
#define ROWS 16
#define LSTR 136              // padded bf16 row stride for activations (2-way conflict = free)
#define OUTSTRIDE (SEQT*NFEAT)

// d_ws layout (same as R1/R2):
#define WFRAG_ELEMS 262144
#define WOUT_ELEMS  4096
#define BIAS_F32OFF (532480/4)
#define BOUT_F32OFF (536576/4)

// LDS byte offsets: [0,131072) weight tail frags; act 6 bufs; bias f32; bout
#define ACT_OFF  131072
#define BIAS_OFF 157184
#define BOUT_OFF 161280
#define SMEM_BYTES 161344

__device__ __forceinline__ float fsig(float x) {
  return __builtin_amdgcn_rcpf(1.0f + __builtin_amdgcn_exp2f(-1.442695041f * x));
}
__device__ __forceinline__ float ftanh(float x) {
  float e = __builtin_amdgcn_exp2f(-2.885390082f * x);   // = exp(-2x)
  return __builtin_fmaf(2.0f, __builtin_amdgcn_rcpf(1.0f + e), -1.0f);
}
__device__ __forceinline__ unsigned short f2bf(float x) {
  __hip_bfloat16 h = __float2bfloat16(x);
  return __builtin_bit_cast(unsigned short, h);
}

// ---------------- setup: repack weights into MFMA fragment order (bf16) ----------------
__global__ void setup_kernel(const float* __restrict__ Wih0, const float* __restrict__ Whh0,
                             const float* __restrict__ bih0, const float* __restrict__ bhh0,
                             const float* __restrict__ Wih1, const float* __restrict__ Whh1,
                             const float* __restrict__ bih1, const float* __restrict__ bhh1,
                             const float* __restrict__ Wo,   const float* __restrict__ bo,
                             unsigned short* __restrict__ ws)
{
  int idx = blockIdx.x * blockDim.x + threadIdx.x;
  if (idx < WFRAG_ELEMS) {
    // A-frag (weights): lane&15 = gate-dim, k=(lane>>4)*8+e over [x(128)|h(128)]
    int e = idx & 7, lane = (idx >> 3) & 63, s = (idx >> 9) & 7, g = (idx >> 12) & 3,
        w = (idx >> 14) & 7, l = idx >> 17;
    int row = g * 128 + w * 16 + (lane & 15);
    int k   = s * 32 + (lane >> 4) * 8 + e;
    const float* Wih = l ? Wih1 : Wih0;
    const float* Whh = l ? Whh1 : Whh0;
    float v = (k < HDIM) ? Wih[row * HDIM + k] : Whh[row * HDIM + (k - HDIM)];
    ws[idx] = f2bf(v);
  } else if (idx < WFRAG_ELEMS + WOUT_ELEMS) {
    int i2 = idx - WFRAG_ELEMS;
    int e = i2 & 7, lane = (i2 >> 3) & 63, s = i2 >> 9;
    int c = lane & 15;
    int k = s * 32 + (lane >> 4) * 8 + e;           // k over [z0(128) | z1(128)]
    float v = (c < NFEAT) ? Wo[c * 256 + k] : 0.0f;
    ws[idx] = f2bf(v);
  } else if (idx < WFRAG_ELEMS + WOUT_ELEMS + 1024) {
    int i3 = idx - (WFRAG_ELEMS + WOUT_ELEMS);
    int l = i3 >> 9, r = i3 & 511;
    float v = l ? (bih1[r] + bhh1[r]) : (bih0[r] + bhh0[r]);
    reinterpret_cast<float*>(ws)[BIAS_F32OFF + i3] = v;
  } else if (idx < WFRAG_ELEMS + WOUT_ELEMS + 1024 + 16) {
    int i4 = idx - (WFRAG_ELEMS + WOUT_ELEMS + 1024);
    reinterpret_cast<float*>(ws)[BOUT_F32OFF + i4] = (i4 < NFEAT) ? bo[i4] : 0.0f;
  }
}

// ---------------- main: 256 blocks x 512 threads; weights pinned in VGPR + LDS ----------------
__global__ __launch_bounds__(512, 2) void lstm_kernel(
    const float* __restrict__ ench, const float* __restrict__ encc,
    const unsigned short* __restrict__ wfrag, const unsigned short* __restrict__ woutf,
    const float* __restrict__ biasc, const float* __restrict__ boutc,
    float* __restrict__ out)
{
  __shared__ __align__(16) unsigned char smem[SMEM_BYTES];
  bf16x8* wlds = reinterpret_cast<bf16x8*>(smem);
  unsigned short* act = reinterpret_cast<unsigned short*>(smem + ACT_OFF);

  const int tid  = threadIdx.x;
  const int wave = tid >> 6, lane = tid & 63;
  const int col  = lane & 15, lg = lane >> 4;
  const int n0   = blockIdx.x * ROWS;
  const int dbase = wave * 16 + lg * 4;

  // ---- persistent weight fragments: s=0..5 pinned in VGPRs, s=6..7 in LDS ----
  bf16x8 wreg[2][4][6];
  const bf16x8* wfv = reinterpret_cast<const bf16x8*>(wfrag);
  #pragma unroll
  for (int l = 0; l < 2; ++l)
    #pragma unroll
    for (int g = 0; g < 4; ++g) {
      #pragma unroll
      for (int s = 0; s < 6; ++s)
        wreg[l][g][s] = wfv[(size_t)((((l * 8 + wave) * 4 + g) * 8) + s) * 64 + lane];
      #pragma unroll
      for (int si = 0; si < 2; ++si)
        wlds[(((wave * 2 + l) * 4 + g) * 2 + si) * 64 + lane] =
            wfv[(size_t)((((l * 8 + wave) * 4 + g) * 8) + 6 + si) * 64 + lane];
    }
  // pin: make values opaque so the compiler cannot re-load them in the loop
  #pragma unroll
  for (int l = 0; l < 2; ++l)
    #pragma unroll
    for (int g = 0; g < 4; ++g)
      #pragma unroll
      for (int s = 0; s < 6; ++s) {
        f32x4 tmp = __builtin_bit_cast(f32x4, wreg[l][g][s]);
        asm volatile("" : "+v"(tmp));
        wreg[l][g][s] = __builtin_bit_cast(bf16x8, tmp);
      }

  // zero x-ping buffers 0,1 (dec_in0 = 0)
  for (int i = tid; i < 2 * ROWS * LSTR; i += 512) act[i] = 0;
  // initial h layer0 -> buf5
  for (int i = tid; i < ROWS * HDIM; i += 512) {
    int r = i >> 7, d = i & (HDIM - 1);
    act[(5 * ROWS + r) * LSTR + d] = f2bf(ench[(n0 + r) * HDIM + d]);
  }
  // bias -> LDS  (256 entries of f32x4: [l][g][wave][lg])
  for (int i = tid; i < 256; i += 512) {
    int l = i >> 7, g = (i >> 5) & 3, w = (i >> 2) & 7, q = i & 3;
    f32x4 b = *reinterpret_cast<const f32x4*>(&biasc[l * 512 + g * 128 + w * 16 + q * 4]);
    *reinterpret_cast<f32x4*>(smem + BIAS_OFF + i * 16) = b;
  }
  if (tid < 16) reinterpret_cast<float*>(smem + BOUT_OFF)[tid] = boutc[tid];
  // c-state: lane holds batch n0+col, dims dbase..dbase+3
  f32x4 c0 = *reinterpret_cast<const f32x4*>(&encc[(size_t)(n0 + col) * HDIM + dbase]);
  f32x4 c1 = *reinterpret_cast<const f32x4*>(&encc[(size_t)(NBATCH + n0 + col) * HDIM + dbase]);
  __syncthreads();

  const int aoffl = col * LSTR + lg * 8;

  auto load4 = [&](int buf, bf16x8 (&a)[4]) {
    const unsigned short* p = act + buf * (ROWS * LSTR) + aoffl;
    #pragma unroll
    for (int s = 0; s < 4; ++s)
      a[s] = *reinterpret_cast<const bf16x8*>(&p[s * 32]);
  };
  auto load4_e1 = [&](bf16x8 (&a)[4]) {      // t=0 layer-1 h straight from global (f32->bf16)
    const float* p = ench + (size_t)(NBATCH + n0 + col) * HDIM + lg * 8;
    #pragma unroll
    for (int s = 0; s < 4; ++s) {
      f32x4 u = *reinterpret_cast<const f32x4*>(&p[s * 32]);
      f32x4 v = *reinterpret_cast<const f32x4*>(&p[s * 32 + 4]);
      bf16x8 r;
      r[0] = (short)f2bf(u[0]); r[1] = (short)f2bf(u[1]);
      r[2] = (short)f2bf(u[2]); r[3] = (short)f2bf(u[3]);
      r[4] = (short)f2bf(v[0]); r[5] = (short)f2bf(v[1]);
      r[6] = (short)f2bf(v[2]); r[7] = (short)f2bf(v[3]);
      a[s] = r;
    }
  };

  auto run_cell = [&](const bf16x8 (&xa)[4], const bf16x8 (&ha)[4], int ob,
                      const bf16x8 (&wr)[4][6], int lb, int bl, f32x4& c) {
    f32x4 acc[4];
    #pragma unroll
    for (int g = 0; g < 4; ++g)
      acc[g] = *reinterpret_cast<const f32x4*>(
          smem + BIAS_OFF + (size_t)(bl * 128 + g * 32 + wave * 4 + lg) * 16);
    #pragma unroll
    for (int s = 0; s < 4; ++s)                        // k = x-half (VGPR weights)
      #pragma unroll
      for (int g = 0; g < 4; ++g)
        acc[g] = __builtin_amdgcn_mfma_f32_16x16x32_bf16(wr[g][s], xa[s], acc[g], 0, 0, 0);
    #pragma unroll
    for (int s = 0; s < 2; ++s)                        // k = h-half, VGPR weights
      #pragma unroll
      for (int g = 0; g < 4; ++g)
        acc[g] = __builtin_amdgcn_mfma_f32_16x16x32_bf16(wr[g][4 + s], ha[s], acc[g], 0, 0, 0);
    #pragma unroll
    for (int si = 0; si < 2; ++si)                     // k = h-half tail, LDS weights
      #pragma unroll
      for (int g = 0; g < 4; ++g) {
        bf16x8 wf = wlds[(lb + g * 2 + si) * 64 + lane];
        acc[g] = __builtin_amdgcn_mfma_f32_16x16x32_bf16(wf, ha[2 + si], acc[g], 0, 0, 0);
      }
    // gates: i,f,g,o ; lane: batch col, dims dbase..dbase+3
    unsigned int p0, p1;
    {
      float cn0 = fsig(acc[1][0]) * c[0] + fsig(acc[0][0]) * ftanh(acc[2][0]);
      float cn1 = fsig(acc[1][1]) * c[1] + fsig(acc[0][1]) * ftanh(acc[2][1]);
      float cn2 = fsig(acc[1][2]) * c[2] + fsig(acc[0][2]) * ftanh(acc[2][2]);
      float cn3 = fsig(acc[1][3]) * c[3] + fsig(acc[0][3]) * ftanh(acc[2][3]);
      c[0] = cn0; c[1] = cn1; c[2] = cn2; c[3] = cn3;
      unsigned int h0 = f2bf(fsig(acc[3][0]) * ftanh(cn0));
      unsigned int h1 = f2bf(fsig(acc[3][1]) * ftanh(cn1));
      unsigned int h2 = f2bf(fsig(acc[3][2]) * ftanh(cn2));
      unsigned int h3 = f2bf(fsig(acc[3][3]) * ftanh(cn3));
      p0 = h0 | (h1 << 16); p1 = h2 | (h3 << 16);
    }
    uint2* op = reinterpret_cast<uint2*>(act + ob * (ROWS * LSTR) + col * LSTR + dbase);
    *op = make_uint2(p0, p1);
    __syncthreads();
  };

  const int lb0 = (wave * 2 + 0) * 8;
  const int lb1 = (wave * 2 + 1) * 8;
  const bf16x8* wov = reinterpret_cast<const bf16x8*>(woutf);

  bf16x8 xa[4], ha[4];
  for (int t = 0; t < SEQT; ++t) {
    const int xA = (t & 1) ? 2 : 0, xB = xA + 1;
    const int zA = (t & 1) ? 0 : 2, zB = zA + 1;
    load4(xA, xa); load4(5, ha);
    run_cell(xa, ha, 4, wreg[0], lb0, 0, c0);          // L0 t0
    load4(xB, xa); load4(4, ha);
    run_cell(xa, ha, 5, wreg[0], lb0, 0, c0);          // L0 t1
    load4(4, xa);
    if (t == 0) load4_e1(ha); else load4(xB, ha);
    run_cell(xa, ha, zA, wreg[1], lb1, 1, c1);         // L1 t0
    load4(5, xa); load4(zA, ha);
    run_cell(xa, ha, zB, wreg[1], lb1, 1, c1);         // L1 t1
    if (wave == 0) {                                   // output projection
      bf16x8 za[4], zb[4];
      load4(zA, za); load4(zB, zb);
      f32x4 po = *reinterpret_cast<const f32x4*>(smem + BOUT_OFF + lg * 16);
      #pragma unroll
      for (int s = 0; s < 4; ++s)
        po = __builtin_amdgcn_mfma_f32_16x16x32_bf16(wov[s * 64 + lane], za[s], po, 0, 0, 0);
      #pragma unroll
      for (int s = 0; s < 4; ++s)
        po = __builtin_amdgcn_mfma_f32_16x16x32_bf16(wov[(4 + s) * 64 + lane], zb[s], po, 0, 0, 0);
      if (lg < 3) {
        f32x4 r;
        r[0] = fsig(po[0]); r[1] = fsig(po[1]); r[2] = fsig(po[2]); r[3] = fsig(po[3]);
        *reinterpret_cast<f32x4*>(&out[(size_t)(n0 + col) * OUTSTRIDE + t * NFEAT + lg * 4]) = r;
      }
    }
  }
}

extern "C" void kernel_launch(void* const* d_in, const int* in_sizes, int n_in,
                              void* d_out, int out_size, void* d_ws, size_t ws_size,
                              hipStream_t stream) {
  const float* ench = (const float*)d_in[0];
  const float* encc = (const float*)d_in[1];
  const float* Wih0 = (const float*)d_in[2];
  const float* Whh0 = (const float*)d_in[3];
  const float* bih0 = (const float*)d_in[4];
  const float* bhh0 = (const float*)d_in[5];
  const float* Wih1 = (const float*)d_in[6];
  const float* Whh1 = (const float*)d_in[7];
  const float* bih1 = (const float*)d_in[8];
  const float* bhh1 = (const float*)d_in[9];
  const float* Wo   = (const float*)d_in[10];
  const float* bo   = (const float*)d_in[11];
  unsigned short* ws = (unsigned short*)d_ws;

  int total = WFRAG_ELEMS + WOUT_ELEMS + 1024 + 16;
  int blocks = (total + 511) / 512;
  hipLaunchKernelGGL(setup_kernel, dim3(blocks), dim3(512), 0, stream,
                     Wih0, Whh0, bih0, bhh0, Wih1, Whh1, bih1, bhh1, Wo, bo, ws);

  const unsigned short* wfrag = ws;
  const unsigned short* woutf = ws + WFRAG_ELEMS;
  const float* biasc = reinterpret_cast<const float*>(ws) + BIAS_F32OFF;
  const float* boutc = reinterpret_cast<const float*>(ws) + BOUT_F32OFF;

  hipLaunchKernelGGL(lstm_kernel, dim3(NBATCH / ROWS), dim3(512), 0, stream,
                     ench, encc, wfrag, woutf, biasc, boutc, (float*)d_out);
}

// Round 4
// 2138.910 us; speedup vs baseline: 1.5948x; 1.0000x over previous
//
#include <hip/hip_runtime.h>
#include <hip/hip_bf16.h>

typedef __attribute__((ext_vector_type(8))) short bf16x8;
typedef __attribute__((ext_vector_type(4))) float f32x4;

#define NBATCH 4096
#define SEQT 181
#define NFEAT 12
#define HDIM 128
#define ROWS 16
#define LSTR 136              // padded bf16 row stride for activations (2-way conflict = free)
#define OUTSTRIDE (SEQT*NFEAT)

// d_ws layout (same as R1/R2/R3):
#define WFRAG_ELEMS 262144
#define WOUT_ELEMS  4096
#define BIAS_F32OFF (532480/4)
#define BOUT_F32OFF (536576/4)

// LDS byte offsets: [0,131072) weight tail frags; act 6 bufs; bias f32; bout
#define ACT_OFF  131072
#define BIAS_OFF 157184
#define BOUT_OFF 161280
#define SMEM_BYTES 161344

__device__ __forceinline__ float fsig(float x) {
  return __builtin_amdgcn_rcpf(1.0f + __builtin_amdgcn_exp2f(-1.442695041f * x));
}
__device__ __forceinline__ float ftanh(float x) {
  float e = __builtin_amdgcn_exp2f(-2.885390082f * x);   // = exp(-2x)
  return __builtin_fmaf(2.0f, __builtin_amdgcn_rcpf(1.0f + e), -1.0f);
}
__device__ __forceinline__ unsigned short f2bf(float x) {
  __hip_bfloat16 h = __float2bfloat16(x);
  return __builtin_bit_cast(unsigned short, h);
}

// ---------------- setup: repack weights into MFMA fragment order (bf16) ----------------
__global__ void setup_kernel(const float* __restrict__ Wih0, const float* __restrict__ Whh0,
                             const float* __restrict__ bih0, const float* __restrict__ bhh0,
                             const float* __restrict__ Wih1, const float* __restrict__ Whh1,
                             const float* __restrict__ bih1, const float* __restrict__ bhh1,
                             const float* __restrict__ Wo,   const float* __restrict__ bo,
                             unsigned short* __restrict__ ws)
{
  int idx = blockIdx.x * blockDim.x + threadIdx.x;
  if (idx < WFRAG_ELEMS) {
    // A-frag (weights): lane&15 = gate-dim, k=(lane>>4)*8+e over [x(128)|h(128)]
    int e = idx & 7, lane = (idx >> 3) & 63, s = (idx >> 9) & 7, g = (idx >> 12) & 3,
        w = (idx >> 14) & 7, l = idx >> 17;
    int row = g * 128 + w * 16 + (lane & 15);
    int k   = s * 32 + (lane >> 4) * 8 + e;
    const float* Wih = l ? Wih1 : Wih0;
    const float* Whh = l ? Whh1 : Whh0;
    float v = (k < HDIM) ? Wih[row * HDIM + k] : Whh[row * HDIM + (k - HDIM)];
    ws[idx] = f2bf(v);
  } else if (idx < WFRAG_ELEMS + WOUT_ELEMS) {
    int i2 = idx - WFRAG_ELEMS;
    int e = i2 & 7, lane = (i2 >> 3) & 63, s = i2 >> 9;
    int c = lane & 15;
    int k = s * 32 + (lane >> 4) * 8 + e;           // k over [z0(128) | z1(128)]
    float v = (c < NFEAT) ? Wo[c * 256 + k] : 0.0f;
    ws[idx] = f2bf(v);
  } else if (idx < WFRAG_ELEMS + WOUT_ELEMS + 1024) {
    int i3 = idx - (WFRAG_ELEMS + WOUT_ELEMS);
    int l = i3 >> 9, r = i3 & 511;
    float v = l ? (bih1[r] + bhh1[r]) : (bih0[r] + bhh0[r]);
    reinterpret_cast<float*>(ws)[BIAS_F32OFF + i3] = v;
  } else if (idx < WFRAG_ELEMS + WOUT_ELEMS + 1024 + 16) {
    int i4 = idx - (WFRAG_ELEMS + WOUT_ELEMS + 1024);
    reinterpret_cast<float*>(ws)[BOUT_F32OFF + i4] = (i4 < NFEAT) ? bo[i4] : 0.0f;
  }
}

// ---------------- main: 256 blocks x 512 threads; weights pinned in VGPR + LDS ----------------
// waves_per_eu(2,2): LDS (161KB) already caps at 1 block/CU = 2 waves/SIMD; telling the
// allocator both min AND max = 2 gives it the full 256-VGPR budget so the 192 pinned
// weight VGPRs stay allocated instead of being spilled/rematerialized per cell.
__global__ void __launch_bounds__(512) __attribute__((amdgpu_waves_per_eu(2, 2)))
lstm_kernel(
    const float* __restrict__ ench, const float* __restrict__ encc,
    const unsigned short* __restrict__ wfrag, const unsigned short* __restrict__ woutf,
    const float* __restrict__ biasc, const float* __restrict__ boutc,
    float* __restrict__ out)
{
  __shared__ __align__(16) unsigned char smem[SMEM_BYTES];
  bf16x8* wlds = reinterpret_cast<bf16x8*>(smem);
  unsigned short* act = reinterpret_cast<unsigned short*>(smem + ACT_OFF);

  const int tid  = threadIdx.x;
  const int wave = tid >> 6, lane = tid & 63;
  const int col  = lane & 15, lg = lane >> 4;
  const int n0   = blockIdx.x * ROWS;
  const int dbase = wave * 16 + lg * 4;

  // ---- persistent weight fragments: s=0..5 pinned in VGPRs, s=6..7 in LDS ----
  bf16x8 wreg[2][4][6];
  const bf16x8* wfv = reinterpret_cast<const bf16x8*>(wfrag);
  #pragma unroll
  for (int l = 0; l < 2; ++l)
    #pragma unroll
    for (int g = 0; g < 4; ++g) {
      #pragma unroll
      for (int s = 0; s < 6; ++s)
        wreg[l][g][s] = wfv[(size_t)((((l * 8 + wave) * 4 + g) * 8) + s) * 64 + lane];
      #pragma unroll
      for (int si = 0; si < 2; ++si)
        wlds[(((wave * 2 + l) * 4 + g) * 2 + si) * 64 + lane] =
            wfv[(size_t)((((l * 8 + wave) * 4 + g) * 8) + 6 + si) * 64 + lane];
    }
  // pin: make values opaque so the compiler cannot re-load them in the loop
  #pragma unroll
  for (int l = 0; l < 2; ++l)
    #pragma unroll
    for (int g = 0; g < 4; ++g)
      #pragma unroll
      for (int s = 0; s < 6; ++s) {
        f32x4 tmp = __builtin_bit_cast(f32x4, wreg[l][g][s]);
        asm volatile("" : "+v"(tmp));
        wreg[l][g][s] = __builtin_bit_cast(bf16x8, tmp);
      }

  // zero x-ping buffers 0,1 (dec_in0 = 0)
  for (int i = tid; i < 2 * ROWS * LSTR; i += 512) act[i] = 0;
  // initial h layer0 -> buf5
  for (int i = tid; i < ROWS * HDIM; i += 512) {
    int r = i >> 7, d = i & (HDIM - 1);
    act[(5 * ROWS + r) * LSTR + d] = f2bf(ench[(n0 + r) * HDIM + d]);
  }
  // bias -> LDS  (256 entries of f32x4: [l][g][wave][lg])
  for (int i = tid; i < 256; i += 512) {
    int l = i >> 7, g = (i >> 5) & 3, w = (i >> 2) & 7, q = i & 3;
    f32x4 b = *reinterpret_cast<const f32x4*>(&biasc[l * 512 + g * 128 + w * 16 + q * 4]);
    *reinterpret_cast<f32x4*>(smem + BIAS_OFF + i * 16) = b;
  }
  if (tid < 16) reinterpret_cast<float*>(smem + BOUT_OFF)[tid] = boutc[tid];
  // c-state: lane holds batch n0+col, dims dbase..dbase+3
  f32x4 c0 = *reinterpret_cast<const f32x4*>(&encc[(size_t)(n0 + col) * HDIM + dbase]);
  f32x4 c1 = *reinterpret_cast<const f32x4*>(&encc[(size_t)(NBATCH + n0 + col) * HDIM + dbase]);
  __syncthreads();

  const int aoffl = col * LSTR + lg * 8;

  auto load4 = [&](int buf, bf16x8 (&a)[4]) {
    const unsigned short* p = act + buf * (ROWS * LSTR) + aoffl;
    #pragma unroll
    for (int s = 0; s < 4; ++s)
      a[s] = *reinterpret_cast<const bf16x8*>(&p[s * 32]);
  };
  auto load4_e1 = [&](bf16x8 (&a)[4]) {      // t=0 layer-1 h straight from global (f32->bf16)
    const float* p = ench + (size_t)(NBATCH + n0 + col) * HDIM + lg * 8;
    #pragma unroll
    for (int s = 0; s < 4; ++s) {
      f32x4 u = *reinterpret_cast<const f32x4*>(&p[s * 32]);
      f32x4 v = *reinterpret_cast<const f32x4*>(&p[s * 32 + 4]);
      bf16x8 r;
      r[0] = (short)f2bf(u[0]); r[1] = (short)f2bf(u[1]);
      r[2] = (short)f2bf(u[2]); r[3] = (short)f2bf(u[3]);
      r[4] = (short)f2bf(v[0]); r[5] = (short)f2bf(v[1]);
      r[6] = (short)f2bf(v[2]); r[7] = (short)f2bf(v[3]);
      a[s] = r;
    }
  };

  auto run_cell = [&](const bf16x8 (&xa)[4], const bf16x8 (&ha)[4], int ob,
                      const bf16x8 (&wr)[4][6], int lb, int bl, f32x4& c) {
    f32x4 acc[4];
    #pragma unroll
    for (int g = 0; g < 4; ++g)
      acc[g] = *reinterpret_cast<const f32x4*>(
          smem + BIAS_OFF + (size_t)(bl * 128 + g * 32 + wave * 4 + lg) * 16);
    #pragma unroll
    for (int s = 0; s < 4; ++s)                        // k = x-half (VGPR weights)
      #pragma unroll
      for (int g = 0; g < 4; ++g)
        acc[g] = __builtin_amdgcn_mfma_f32_16x16x32_bf16(wr[g][s], xa[s], acc[g], 0, 0, 0);
    #pragma unroll
    for (int s = 0; s < 2; ++s)                        // k = h-half, VGPR weights
      #pragma unroll
      for (int g = 0; g < 4; ++g)
        acc[g] = __builtin_amdgcn_mfma_f32_16x16x32_bf16(wr[g][4 + s], ha[s], acc[g], 0, 0, 0);
    #pragma unroll
    for (int si = 0; si < 2; ++si)                     // k = h-half tail, LDS weights
      #pragma unroll
      for (int g = 0; g < 4; ++g) {
        bf16x8 wf = wlds[(lb + g * 2 + si) * 64 + lane];
        acc[g] = __builtin_amdgcn_mfma_f32_16x16x32_bf16(wf, ha[2 + si], acc[g], 0, 0, 0);
      }
    // gates: i,f,g,o ; lane: batch col, dims dbase..dbase+3
    unsigned int p0, p1;
    {
      float cn0 = fsig(acc[1][0]) * c[0] + fsig(acc[0][0]) * ftanh(acc[2][0]);
      float cn1 = fsig(acc[1][1]) * c[1] + fsig(acc[0][1]) * ftanh(acc[2][1]);
      float cn2 = fsig(acc[1][2]) * c[2] + fsig(acc[0][2]) * ftanh(acc[2][2]);
      float cn3 = fsig(acc[1][3]) * c[3] + fsig(acc[0][3]) * ftanh(acc[2][3]);
      c[0] = cn0; c[1] = cn1; c[2] = cn2; c[3] = cn3;
      unsigned int h0 = f2bf(fsig(acc[3][0]) * ftanh(cn0));
      unsigned int h1 = f2bf(fsig(acc[3][1]) * ftanh(cn1));
      unsigned int h2 = f2bf(fsig(acc[3][2]) * ftanh(cn2));
      unsigned int h3 = f2bf(fsig(acc[3][3]) * ftanh(cn3));
      p0 = h0 | (h1 << 16); p1 = h2 | (h3 << 16);
    }
    uint2* op = reinterpret_cast<uint2*>(act + ob * (ROWS * LSTR) + col * LSTR + dbase);
    *op = make_uint2(p0, p1);
    __syncthreads();
  };

  const int lb0 = (wave * 2 + 0) * 8;
  const int lb1 = (wave * 2 + 1) * 8;
  const bf16x8* wov = reinterpret_cast<const bf16x8*>(woutf);

  bf16x8 xa[4], ha[4];
  for (int t = 0; t < SEQT; ++t) {
    const int xA = (t & 1) ? 2 : 0, xB = xA + 1;
    const int zA = (t & 1) ? 0 : 2, zB = zA + 1;
    load4(xA, xa); load4(5, ha);
    run_cell(xa, ha, 4, wreg[0], lb0, 0, c0);          // L0 t0
    load4(xB, xa); load4(4, ha);
    run_cell(xa, ha, 5, wreg[0], lb0, 0, c0);          // L0 t1
    load4(4, xa);
    if (t == 0) load4_e1(ha); else load4(xB, ha);
    run_cell(xa, ha, zA, wreg[1], lb1, 1, c1);         // L1 t0
    load4(5, xa); load4(zA, ha);
    run_cell(xa, ha, zB, wreg[1], lb1, 1, c1);         // L1 t1
    if (wave == 0) {                                   // output projection
      bf16x8 za[4], zb[4];
      load4(zA, za); load4(zB, zb);
      f32x4 po = *reinterpret_cast<const f32x4*>(smem + BOUT_OFF + lg * 16);
      #pragma unroll
      for (int s = 0; s < 4; ++s)
        po = __builtin_amdgcn_mfma_f32_16x16x32_bf16(wov[s * 64 + lane], za[s], po, 0, 0, 0);
      #pragma unroll
      for (int s = 0; s < 4; ++s)
        po = __builtin_amdgcn_mfma_f32_16x16x32_bf16(wov[(4 + s) * 64 + lane], zb[s], po, 0, 0, 0);
      if (lg < 3) {
        f32x4 r;
        r[0] = fsig(po[0]); r[1] = fsig(po[1]); r[2] = fsig(po[2]); r[3] = fsig(po[3]);
        *reinterpret_cast<f32x4*>(&out[(size_t)(n0 + col) * OUTSTRIDE + t * NFEAT + lg * 4]) = r;
      }
    }
  }
}

extern "C" void kernel_launch(void* const* d_in, const int* in_sizes, int n_in,
                              void* d_out, int out_size, void* d_ws, size_t ws_size,
                              hipStream_t stream) {
  const float* ench = (const float*)d_in[0];
  const float* encc = (const float*)d_in[1];
  const float* Wih0 = (const float*)d_in[2];
  const float* Whh0 = (const float*)d_in[3];
  const float* bih0 = (const float*)d_in[4];
  const float* bhh0 = (const float*)d_in[5];
  const float* Wih1 = (const float*)d_in[6];
  const float* Whh1 = (const float*)d_in[7];
  const float* bih1 = (const float*)d_in[8];
  const float* bhh1 = (const float*)d_in[9];
  const float* Wo   = (const float*)d_in[10];
  const float* bo   = (const float*)d_in[11];
  unsigned short* ws = (unsigned short*)d_ws;

  int total = WFRAG_ELEMS + WOUT_ELEMS + 1024 + 16;
  int blocks = (total + 511) / 512;
  hipLaunchKernelGGL(setup_kernel, dim3(blocks), dim3(512), 0, stream,
                     Wih0, Whh0, bih0, bhh0, Wih1, Whh1, bih1, bhh1, Wo, bo, ws);

  const unsigned short* wfrag = ws;
  const unsigned short* woutf = ws + WFRAG_ELEMS;
  const float* biasc = reinterpret_cast<const float*>(ws) + BIAS_F32OFF;
  const float* boutc = reinterpret_cast<const float*>(ws) + BOUT_F32OFF;

  hipLaunchKernelGGL(lstm_kernel, dim3(NBATCH / ROWS), dim3(512), 0, stream,
                     ench, encc, wfrag, woutf, biasc, boutc, (float*)d_out);
}